// Round 1
// 734.717 us; speedup vs baseline: 1.1303x; 1.1303x over previous
//
#include <hip/hip_runtime.h>
#include <stdint.h>

// Problem: B=256, P=196, ENC=2048, DEC=512, ATT=512. All tensors fp32 on device.
// Pipeline:
//   k0: W_enc fp32[2048][512] -> wencT bf16, TILED+SWIZZLED: 64 K-step tiles of
//       32 KB, tile[ks] holds B[n][k] (n=0..511, k=ks*32..+31) at ushort index
//       (n*32 + k') ^ ((n&7)<<3)  -- the exact LDS image gemm_att wants, so
//       global_load_lds can stage it linearly (rule: linear dest + pre-swizzled
//       source + swizzled read).
//   k1: comb[b][a] = dec[b]*W_dec[:,a] + b_dec[a] + b_enc[a]   (256 blocks)
//   k2: att[r] = sum_a relu(enc_row_r * W_enc[:,a] + comb) * W_full[a]
//       64-row x 512-col tiles, 8 waves, bf16 MFMA fp32-accum, double-buffered
//       A(LDS,swizzled)+B(LDS via glds), ONE raw s_barrier per K-step,
//       loads issued early / consumed late (async-stage split).
//   k3: alpha = softmax_P(att); context = sum_p alpha[p]*enc[b,p,:]
//       2 e-slices per batch (grid 512) for occupancy; pure fp32.
// (b_full omitted: softmax is shift-invariant.)

using u16x8 = __attribute__((ext_vector_type(8))) unsigned short;
using s16x8 = __attribute__((ext_vector_type(8))) short;
using f32x4 = __attribute__((ext_vector_type(4))) float;

typedef __attribute__((address_space(1))) const void gvoid_t;
typedef __attribute__((address_space(3))) void lvoid_t;

static __device__ __forceinline__ unsigned short f2b(float f) {  // RNE fp32->bf16
  unsigned int u = __builtin_bit_cast(unsigned int, f);
  u = u + 0x7fffu + ((u >> 16) & 1u);
  return (unsigned short)(u >> 16);
}

static __device__ __forceinline__ void glds16(const void* g, void* l) {
  __builtin_amdgcn_global_load_lds((gvoid_t*)g, (lvoid_t*)l, 16, 0, 0);
}

// ------------------------------------------------------------- k0: tiled+swizzled W
// 64 tiles x 2048 chunks(16B) = 131072 chunks; one chunk per thread.
__global__ __launch_bounds__(256) void transpose_wenc(
    const float* __restrict__ wenc, unsigned short* __restrict__ wencT) {
  const int g = blockIdx.x * 256 + threadIdx.x;
  const int ks = g >> 11;      // 0..63   K-step tile
  const int c = g & 2047;      // chunk within tile
  const int n = c >> 2;        // 0..511  output column of W (ATT dim)
  const int kc = c & 3;        // 0..3    8-wide k-chunk within the 32-k tile
  const float* src = wenc + (size_t)(ks * 32 + kc * 8) * 512 + n;
  u16x8 v;
#pragma unroll
  for (int j = 0; j < 8; ++j) v[j] = f2b(src[(size_t)j * 512]);
  const int idx = (n * 32 + kc * 8) ^ ((n & 7) << 3);  // XOR swizzle (ushort units)
  *(u16x8*)&wencT[(size_t)ks * 16384 + idx] = v;
}

// ------------------------------------------------------------- k1: comb bias (fp32)
// 256 blocks (1 batch each), 256 threads, 2 outputs/thread, unroll-8 for load ILP.
__global__ __launch_bounds__(256) void comb_kernel(
    const float* __restrict__ dec, const float* __restrict__ wdec,
    const float* __restrict__ bdec, const float* __restrict__ benc,
    float* __restrict__ comb) {
  __shared__ float dec_sh[512];
  const int b = blockIdx.x, t = threadIdx.x;
  dec_sh[t] = dec[(size_t)b * 512 + t];
  dec_sh[256 + t] = dec[(size_t)b * 512 + 256 + t];
  __syncthreads();
  const int a0 = 2 * t;
  float acc0 = bdec[a0] + benc[a0];
  float acc1 = bdec[a0 + 1] + benc[a0 + 1];
#pragma unroll 8
  for (int e = 0; e < 512; ++e) {
    float2 wv = *(const float2*)&wdec[(size_t)e * 512 + a0];
    float d = dec_sh[e];
    acc0 = fmaf(d, wv.x, acc0);
    acc1 = fmaf(d, wv.y, acc1);
  }
  *(float2*)&comb[(size_t)b * 512 + a0] = make_float2(acc0, acc1);
}

// ------------------------------------------------------------- k2: MFMA GEMM + reduce
// 64 rows x 512 cols per block, BK=32, 512 threads = 8 waves (2m x 4n).
// Double-buffered LDS, one raw s_barrier per K-step.
__global__ __launch_bounds__(512, 4) void gemm_att(
    const float* __restrict__ enc, const unsigned short* __restrict__ wencT,
    const float* __restrict__ comb, const float* __restrict__ wfull_g,
    float* __restrict__ att) {
  __shared__ alignas(16) unsigned short Bsh[2][16384];  // 2 x 32 KB (glds image)
  __shared__ alignas(16) unsigned short Ash[2][2048];   // 2 x 4 KB (swizzled)
  __shared__ float comb_sh[1024];
  __shared__ float wfull_sh[512];
  __shared__ float att_sh[64];

  const int t = threadIdx.x;
  const int l = t & 63;
  const int quad = l >> 4, col = l & 15;
  const int w = t >> 6;
  const int wm = w >> 2, wn = w & 3;
  const int r0 = blockIdx.x * 64;
  const int b0 = r0 / 196;
  const int rsw = (b0 + 1) * 196;  // rows >= rsw belong to batch b0+1
  const int b1 = (b0 + 1 < 256) ? b0 + 1 : 255;

  comb_sh[t] = comb[(size_t)b0 * 512 + t];
  comb_sh[512 + t] = comb[(size_t)b1 * 512 + t];
  wfull_sh[t] = wfull_g[t];
  if (t < 64) att_sh[t] = 0.0f;

  // ---- A staging (threads 0..255): one u16x8 (row, 8-k chunk) per thread
  const int arow = (t & 255) >> 2, achk = t & 3;
  const float* ap = enc + (size_t)(r0 + arow) * 2048 + achk * 8;
  const int a_lds = (arow * 32 + achk * 8) ^ ((arow & 7) << 3);  // ushort idx

  // ---- B staging: 4 x 16B chunks/thread via global_load_lds (linear copy)
  const unsigned short* bgp[4];
  int blds[4];
#pragma unroll
  for (int j = 0; j < 4; ++j) {
    const int c = j * 512 + t;
    bgp[j] = wencT + (size_t)c * 8;  // tile 0
    blds[j] = c * 8;                 // dest = uniform + lane*16  (glds-legal)
  }

  // ---- fragment offsets (swizzled, ushort units)
  int aoff[2], boff[8];
#pragma unroll
  for (int mt = 0; mt < 2; ++mt) {
    const int row = wm * 32 + mt * 16 + col;
    aoff[mt] = (row * 32 + quad * 8) ^ ((row & 7) << 3);
  }
#pragma unroll
  for (int nt = 0; nt < 8; ++nt) {
    const int n = wn * 128 + nt * 16 + col;
    boff[nt] = (n * 32 + quad * 8) ^ ((n & 7) << 3);
  }

  f32x4 acc[2][8];
#pragma unroll
  for (int mt = 0; mt < 2; ++mt)
#pragma unroll
    for (int nt = 0; nt < 8; ++nt) acc[mt][nt] = (f32x4){0.f, 0.f, 0.f, 0.f};

  // ---- prologue: stage tile 0 into buffer 0
#pragma unroll
  for (int j = 0; j < 4; ++j) {
    glds16(bgp[j], &Bsh[0][blds[j]]);
    bgp[j] += 16384;  // -> tile 1
  }
  if (t < 256) {
    f32x4 a0v = *(const f32x4*)ap;
    f32x4 a1v = *(const f32x4*)(ap + 4);
    u16x8 av;
    av[0] = f2b(a0v[0]); av[1] = f2b(a0v[1]); av[2] = f2b(a0v[2]); av[3] = f2b(a0v[3]);
    av[4] = f2b(a1v[0]); av[5] = f2b(a1v[1]); av[6] = f2b(a1v[2]); av[7] = f2b(a1v[3]);
    *(u16x8*)&Ash[0][a_lds] = av;
  }
  ap += 32;  // -> tile 1
  __syncthreads();  // full drain once: glds landed + ds_write visible

  // ---- main loop: one raw barrier per K-step; prefetch issued early, consumed late
#pragma unroll 2
  for (int ks = 0; ks < 64; ++ks) {
    const int buf = ks & 1, nbuf = buf ^ 1;
    const bool pf = (ks < 63);

    // issue next A loads first (oldest vmem -> compiler waits only these at f2b)
    f32x4 a0v, a1v;
    if (pf && t < 256) {
      a0v = *(const f32x4*)ap;
      a1v = *(const f32x4*)(ap + 4);
    }
    __builtin_amdgcn_sched_barrier(0);
    if (pf) {
#pragma unroll
      for (int j = 0; j < 4; ++j) {
        glds16(bgp[j], &Bsh[nbuf][blds[j]]);
        bgp[j] += 16384;
      }
    }
    __builtin_amdgcn_sched_barrier(0);

    // compute on current buffer
    s16x8 afr0 = *(const s16x8*)&Ash[buf][aoff[0]];
    s16x8 afr1 = *(const s16x8*)&Ash[buf][aoff[1]];
#pragma unroll
    for (int nt = 0; nt < 8; ++nt) {
      s16x8 bfr = *(const s16x8*)&Bsh[buf][boff[nt]];
      acc[0][nt] = __builtin_amdgcn_mfma_f32_16x16x32_bf16(afr0, bfr, acc[0][nt], 0, 0, 0);
      acc[1][nt] = __builtin_amdgcn_mfma_f32_16x16x32_bf16(afr1, bfr, acc[1][nt], 0, 0, 0);
    }
    __builtin_amdgcn_sched_barrier(0);

    // convert+write next A tile (A-load latency covered by the MFMA phase)
    if (pf && t < 256) {
      u16x8 av;
      av[0] = f2b(a0v[0]); av[1] = f2b(a0v[1]); av[2] = f2b(a0v[2]); av[3] = f2b(a0v[3]);
      av[4] = f2b(a1v[0]); av[5] = f2b(a1v[1]); av[6] = f2b(a1v[2]); av[7] = f2b(a1v[3]);
      *(u16x8*)&Ash[nbuf][a_lds] = av;
      ap += 32;
    }
    __builtin_amdgcn_sched_barrier(0);
    asm volatile("s_waitcnt vmcnt(0) lgkmcnt(0)" ::: "memory");
    __builtin_amdgcn_sched_barrier(0);
    __builtin_amdgcn_s_barrier();
  }

  // ---- epilogue: v = relu(C + comb[b][n]); att_row += v * W_full[n]
  __syncthreads();
#pragma unroll
  for (int mt = 0; mt < 2; ++mt) {
#pragma unroll
    for (int r = 0; r < 4; ++r) {
      const int rl = wm * 32 + mt * 16 + quad * 4 + r;  // C/D: row=quad*4+reg
      const int cb = ((r0 + rl) >= rsw) ? 512 : 0;
      float s = 0.f;
#pragma unroll
      for (int nt = 0; nt < 8; ++nt) {
        const int n = wn * 128 + nt * 16 + col;  // C/D: col=lane&15
        float v = acc[mt][nt][r] + comb_sh[cb + n];
        v = fmaxf(v, 0.f);
        s = fmaf(v, wfull_sh[n], s);
      }
      s += __shfl_xor(s, 1);
      s += __shfl_xor(s, 2);
      s += __shfl_xor(s, 4);
      s += __shfl_xor(s, 8);
      if (col == 0) atomicAdd(&att_sh[rl], s);
    }
  }
  __syncthreads();
  if (t < 64) att[(size_t)r0 + t] = att_sh[t];
}

// ------------------------------------------------------------- k3: softmax+context
// grid = 256 batches x 2 e-slices. Softmax computed redundantly per slice (cheap);
// slice 0 writes alpha. Context: 1024 e per block, f32x4/thread, unroll-4 ILP.
__global__ __launch_bounds__(256) void softmax_ctx(
    const float* __restrict__ att, const float* __restrict__ enc,
    float* __restrict__ ctx_out, float* __restrict__ alpha_out) {
  const int b = blockIdx.x >> 1, slice = blockIdx.x & 1;
  const int t = threadIdx.x;
  __shared__ float red[256];
  __shared__ float alpha_sh[196];

  float v = (t < 196) ? att[(size_t)b * 196 + t] : -1e30f;
  red[t] = v;
  __syncthreads();
  for (int s = 128; s > 0; s >>= 1) {
    if (t < s) red[t] = fmaxf(red[t], red[t + s]);
    __syncthreads();
  }
  float mx = red[0];
  __syncthreads();
  float e = (t < 196) ? __expf(v - mx) : 0.f;
  red[t] = e;
  __syncthreads();
  for (int s = 128; s > 0; s >>= 1) {
    if (t < s) red[t] += red[t + s];
    __syncthreads();
  }
  float a = e / red[0];
  if (t < 196) {
    alpha_sh[t] = a;
    if (slice == 0) alpha_out[(size_t)b * 196 + t] = a;
  }
  __syncthreads();

  f32x4 acc = {0.f, 0.f, 0.f, 0.f};
  const float* ep = enc + (size_t)b * 196 * 2048 + slice * 1024 + t * 4;
#pragma unroll 4
  for (int p = 0; p < 196; ++p) {
    float ap = alpha_sh[p];
    f32x4 ev = *(const f32x4*)ep;
    acc[0] = fmaf(ap, ev[0], acc[0]);
    acc[1] = fmaf(ap, ev[1], acc[1]);
    acc[2] = fmaf(ap, ev[2], acc[2]);
    acc[3] = fmaf(ap, ev[3], acc[3]);
    ep += 2048;
  }
  *(f32x4*)(ctx_out + (size_t)b * 2048 + slice * 1024 + t * 4) = acc;
}

// ------------------------------------------------------------- launch
extern "C" void kernel_launch(void* const* d_in, const int* in_sizes, int n_in,
                              void* d_out, int out_size, void* d_ws, size_t ws_size,
                              hipStream_t stream) {
  (void)in_sizes; (void)n_in; (void)out_size; (void)ws_size;
  const float* enc   = (const float*)d_in[0];  // [256,196,2048] fp32
  const float* dec   = (const float*)d_in[1];  // [256,512]
  const float* wenc  = (const float*)d_in[2];  // [2048,512]
  const float* benc  = (const float*)d_in[3];  // [512]
  const float* wdec  = (const float*)d_in[4];  // [512,512]
  const float* bdec  = (const float*)d_in[5];  // [512]
  const float* wfull = (const float*)d_in[6];  // [512]
  // d_in[7] (b_full) unused: softmax is shift-invariant.

  unsigned short* wencT = (unsigned short*)d_ws;                    // 2 MB (tiled)
  float* comb = (float*)((char*)d_ws + (2u << 20));                 // 512 KB
  float* att  = (float*)((char*)d_ws + (2u << 20) + (512u << 10));  // 200 KB

  float* ctx_out = (float*)d_out;                    // [256,2048] fp32
  float* alpha_out = ctx_out + (size_t)256 * 2048;   // [256,196]  fp32

  hipLaunchKernelGGL(transpose_wenc, dim3(512), dim3(256), 0, stream, wenc, wencT);
  hipLaunchKernelGGL(comb_kernel, dim3(256), dim3(256), 0, stream, dec, wdec, bdec, benc, comb);
  hipLaunchKernelGGL(gemm_att, dim3(784), dim3(512), 0, stream, enc, wencT, comb, wfull, att);
  hipLaunchKernelGGL(softmax_ctx, dim3(512), dim3(256), 0, stream, att, enc, ctx_out, alpha_out);
}

// Round 2
// 726.188 us; speedup vs baseline: 1.1436x; 1.0117x over previous
//
#include <hip/hip_runtime.h>
#include <stdint.h>

// Problem: B=256, P=196, ENC=2048, DEC=512, ATT=512. All tensors fp32 on device.
// Pipeline:
//   k0: W_enc fp32[2048][512] -> wencT bf16, TILED+SWIZZLED: 64 K-step tiles of
//       32 KB; tile[ks] holds B[n][k'] at ushort index (n*32+k') ^ ((n&7)<<3).
//       This is the exact LDS image gemm_att wants, so global_load_lds stages it
//       linearly (linear dest + pre-swizzled source + swizzled read).
//   k1: comb[b][a] = dec[b]*W_dec[:,a] + b_dec[a] + b_enc[a]   (256 blocks)
//   k2: att[r] = sum_a relu(enc_row_r * W_enc[:,a] + comb) * W_full[a]
//       64x512 tiles, 8 waves, bf16 MFMA fp32-accum. Pipelined K-loop:
//       B double-buffered via glds (drained with COUNTED vmcnt(1), issued 1 step
//       ahead), A loaded TWO steps ahead into VGPR (f2b conversion + ds_write one
//       step ahead), one raw s_barrier per step, setprio around MFMA.
//   k3: alpha = softmax_P(att); context = sum_p alpha[p]*enc[b,p,:]  (grid 512)
// (b_full omitted: softmax is shift-invariant.)

using u16x8 = __attribute__((ext_vector_type(8))) unsigned short;
using u16x4 = __attribute__((ext_vector_type(4))) unsigned short;
using s16x8 = __attribute__((ext_vector_type(8))) short;
using f32x4 = __attribute__((ext_vector_type(4))) float;

typedef __attribute__((address_space(1))) const void gvoid_t;
typedef __attribute__((address_space(3))) void lvoid_t;

static __device__ __forceinline__ unsigned short f2b(float f) {  // RNE fp32->bf16
  unsigned int u = __builtin_bit_cast(unsigned int, f);
  u = u + 0x7fffu + ((u >> 16) & 1u);
  return (unsigned short)(u >> 16);
}

static __device__ __forceinline__ void glds16(const void* g, void* l) {
  __builtin_amdgcn_global_load_lds((gvoid_t*)g, (lvoid_t*)l, 16, 0, 0);
}

// ------------------------------------------------------------- k0: tiled+swizzled W
__global__ __launch_bounds__(256) void transpose_wenc(
    const float* __restrict__ wenc, unsigned short* __restrict__ wencT) {
  const int g = blockIdx.x * 256 + threadIdx.x;
  const int ks = g >> 11;      // 0..63   K-step tile
  const int c = g & 2047;      // chunk within tile
  const int n = c >> 2;        // 0..511  output column of W (ATT dim)
  const int kc = c & 3;        // 0..3    8-wide k-chunk within the 32-k tile
  const float* src = wenc + (size_t)(ks * 32 + kc * 8) * 512 + n;
  u16x8 v;
#pragma unroll
  for (int j = 0; j < 8; ++j) v[j] = f2b(src[(size_t)j * 512]);
  const int idx = (n * 32 + kc * 8) ^ ((n & 7) << 3);  // XOR swizzle (ushort units)
  *(u16x8*)&wencT[(size_t)ks * 16384 + idx] = v;
}

// ------------------------------------------------------------- k1: comb bias (fp32)
__global__ __launch_bounds__(256) void comb_kernel(
    const float* __restrict__ dec, const float* __restrict__ wdec,
    const float* __restrict__ bdec, const float* __restrict__ benc,
    float* __restrict__ comb) {
  __shared__ float dec_sh[512];
  const int b = blockIdx.x, t = threadIdx.x;
  dec_sh[t] = dec[(size_t)b * 512 + t];
  dec_sh[256 + t] = dec[(size_t)b * 512 + 256 + t];
  __syncthreads();
  const int a0 = 2 * t;
  float acc0 = bdec[a0] + benc[a0];
  float acc1 = bdec[a0 + 1] + benc[a0 + 1];
#pragma unroll 8
  for (int e = 0; e < 512; ++e) {
    float2 wv = *(const float2*)&wdec[(size_t)e * 512 + a0];
    float d = dec_sh[e];
    acc0 = fmaf(d, wv.x, acc0);
    acc1 = fmaf(d, wv.y, acc1);
  }
  *(float2*)&comb[(size_t)b * 512 + a0] = make_float2(acc0, acc1);
}

// ------------------------------------------------------------- k2: MFMA GEMM + reduce
// 64 rows x 512 cols per block, BK=32, 512 threads = 8 waves (2m x 4n).
// LDS 80128 B -> 2 blocks/CU.
__global__ __launch_bounds__(512, 4) void gemm_att(
    const float* __restrict__ enc, const unsigned short* __restrict__ wencT,
    const float* __restrict__ comb, const float* __restrict__ wfull_g,
    float* __restrict__ att) {
  __shared__ alignas(16) unsigned short Bsh[2][16384];  // 2 x 32 KB (glds image)
  __shared__ alignas(16) unsigned short Ash[2][2048];   // 2 x 4 KB (swizzled)
  __shared__ float comb_sh[1024];
  __shared__ float wfull_sh[512];
  __shared__ float att_sh[64];

  const int t = threadIdx.x;
  const int l = t & 63;
  const int quad = l >> 4, col = l & 15;
  const int w = t >> 6;
  const int wm = w >> 2, wn = w & 3;
  const int r0 = blockIdx.x * 64;
  const int b0 = r0 / 196;
  const int rsw = (b0 + 1) * 196;  // rows >= rsw belong to batch b0+1
  const int b1 = (b0 + 1 < 256) ? b0 + 1 : 255;

  comb_sh[t] = comb[(size_t)b0 * 512 + t];
  comb_sh[512 + t] = comb[(size_t)b1 * 512 + t];
  wfull_sh[t] = wfull_g[t];
  if (t < 64) att_sh[t] = 0.0f;

  // ---- A staging: ALL 512 threads, one f32x4 (row, 4-float chunk) per thread
  const int arow = t >> 3, ak4 = t & 7;
  const float* ap = enc + (size_t)(r0 + arow) * 2048 + ak4 * 4;
  const int a_lds = (arow * 32 + ak4 * 4) ^ ((arow & 7) << 3);  // ushort idx

  // ---- B staging: 4 x 16B chunks/thread via global_load_lds (linear dest)
  const unsigned short* bgp[4];
  int blds[4];
#pragma unroll
  for (int j = 0; j < 4; ++j) {
    const int c = j * 512 + t;
    bgp[j] = wencT + (size_t)c * 8;  // tile 0
    blds[j] = c * 8;                 // dest = wave-uniform + lane*16
  }

  // ---- fragment offsets (swizzled, ushort units)
  int aoff[2], boff[8];
#pragma unroll
  for (int mt = 0; mt < 2; ++mt) {
    const int row = wm * 32 + mt * 16 + col;
    aoff[mt] = (row * 32 + quad * 8) ^ ((row & 7) << 3);
  }
#pragma unroll
  for (int nt = 0; nt < 8; ++nt) {
    const int n = wn * 128 + nt * 16 + col;
    boff[nt] = (n * 32 + quad * 8) ^ ((n & 7) << 3);
  }

  f32x4 acc[2][8];
#pragma unroll
  for (int mt = 0; mt < 2; ++mt)
#pragma unroll
    for (int nt = 0; nt < 8; ++nt) acc[mt][nt] = (f32x4){0.f, 0.f, 0.f, 0.f};

  // ---- prologue: B tile0 via glds; A tile0 convert+write; A tile1 into a_hold
#pragma unroll
  for (int j = 0; j < 4; ++j) {
    glds16(bgp[j], &Bsh[0][blds[j]]);
    bgp[j] += 16384;  // -> tile 1
  }
  f32x4 a0v = *(const f32x4*)ap;
  ap += 32;
  f32x4 a_hold = *(const f32x4*)ap;  // tile 1 data
  ap += 32;                          // -> tile 2
  {
    u16x4 av;
    av[0] = f2b(a0v[0]); av[1] = f2b(a0v[1]); av[2] = f2b(a0v[2]); av[3] = f2b(a0v[3]);
    *(u16x4*)&Ash[0][a_lds] = av;
  }
  __syncthreads();  // full drain once: glds tile0 landed + Ash[0] visible

  // ---- main loop (tiles 0..62 computed here; tile 63 in tail)
  for (int ks = 0; ks < 63; ++ks) {
    const int buf = ks & 1, nbuf = buf ^ 1;

    // (1) B prefetch: tile ks+1 -> Bsh[nbuf]   (issued FIRST -> oldest vmem)
#pragma unroll
    for (int j = 0; j < 4; ++j) {
      glds16(bgp[j], &Bsh[nbuf][blds[j]]);
      bgp[j] += 16384;
    }
    __builtin_amdgcn_sched_barrier(0);

    // (2) A prefetch: tile ks+2 (duplicate tile 63 past the end; in-bounds)
    f32x4 a_new = *(const f32x4*)ap;
    if (ks < 61) ap += 32;
    __builtin_amdgcn_sched_barrier(0);

    // (3) MFMA on tile ks
    const unsigned short* Ab = &Ash[buf][0];
    const unsigned short* Bb = &Bsh[buf][0];
    s16x8 afr0 = *(const s16x8*)(Ab + aoff[0]);
    s16x8 afr1 = *(const s16x8*)(Ab + aoff[1]);
    __builtin_amdgcn_s_setprio(1);
#pragma unroll
    for (int nt = 0; nt < 8; ++nt) {
      s16x8 bfr = *(const s16x8*)(Bb + boff[nt]);
      acc[0][nt] = __builtin_amdgcn_mfma_f32_16x16x32_bf16(afr0, bfr, acc[0][nt], 0, 0, 0);
      acc[1][nt] = __builtin_amdgcn_mfma_f32_16x16x32_bf16(afr1, bfr, acc[1][nt], 0, 0, 0);
    }
    __builtin_amdgcn_s_setprio(0);
    __builtin_amdgcn_sched_barrier(0);

    // (4) convert A tile ks+1 (loaded LAST iteration -> ~2 steps of latency slack)
    {
      u16x4 av;
      av[0] = f2b(a_hold[0]); av[1] = f2b(a_hold[1]);
      av[2] = f2b(a_hold[2]); av[3] = f2b(a_hold[3]);
      *(u16x4*)&Ash[nbuf][a_lds] = av;
    }
    a_hold = a_new;
    __builtin_amdgcn_sched_barrier(0);

    // (5) counted drain: finish this step's 4 glds (tile ks+1, needed after the
    //     barrier) but KEEP the newest A-load (tile ks+2) in flight; ds_write
    //     visible via lgkmcnt(0).
    asm volatile("s_waitcnt vmcnt(1) lgkmcnt(0)" ::: "memory");
    __builtin_amdgcn_sched_barrier(0);
    __builtin_amdgcn_s_barrier();
  }

  // ---- tail: MFMA on tile 63 (buf = 1)
  {
    const unsigned short* Ab = &Ash[1][0];
    const unsigned short* Bb = &Bsh[1][0];
    s16x8 afr0 = *(const s16x8*)(Ab + aoff[0]);
    s16x8 afr1 = *(const s16x8*)(Ab + aoff[1]);
#pragma unroll
    for (int nt = 0; nt < 8; ++nt) {
      s16x8 bfr = *(const s16x8*)(Bb + boff[nt]);
      acc[0][nt] = __builtin_amdgcn_mfma_f32_16x16x32_bf16(afr0, bfr, acc[0][nt], 0, 0, 0);
      acc[1][nt] = __builtin_amdgcn_mfma_f32_16x16x32_bf16(afr1, bfr, acc[1][nt], 0, 0, 0);
    }
  }

  // ---- epilogue: v = relu(C + comb[b][n]); att_row += v * W_full[n]
  __syncthreads();
#pragma unroll
  for (int mt = 0; mt < 2; ++mt) {
#pragma unroll
    for (int r = 0; r < 4; ++r) {
      const int rl = wm * 32 + mt * 16 + quad * 4 + r;  // C/D: row=quad*4+reg
      const int cb = ((r0 + rl) >= rsw) ? 512 : 0;
      float s = 0.f;
#pragma unroll
      for (int nt = 0; nt < 8; ++nt) {
        const int n = wn * 128 + nt * 16 + col;  // C/D: col=lane&15
        float v = acc[mt][nt][r] + comb_sh[cb + n];
        v = fmaxf(v, 0.f);
        s = fmaf(v, wfull_sh[n], s);
      }
      s += __shfl_xor(s, 1);
      s += __shfl_xor(s, 2);
      s += __shfl_xor(s, 4);
      s += __shfl_xor(s, 8);
      if (col == 0) atomicAdd(&att_sh[rl], s);
    }
  }
  __syncthreads();
  if (t < 64) att[(size_t)r0 + t] = att_sh[t];
}

// ------------------------------------------------------------- k3: softmax+context
__global__ __launch_bounds__(256) void softmax_ctx(
    const float* __restrict__ att, const float* __restrict__ enc,
    float* __restrict__ ctx_out, float* __restrict__ alpha_out) {
  const int b = blockIdx.x >> 1, slice = blockIdx.x & 1;
  const int t = threadIdx.x;
  __shared__ float red[256];
  __shared__ float alpha_sh[196];

  float v = (t < 196) ? att[(size_t)b * 196 + t] : -1e30f;
  red[t] = v;
  __syncthreads();
  for (int s = 128; s > 0; s >>= 1) {
    if (t < s) red[t] = fmaxf(red[t], red[t + s]);
    __syncthreads();
  }
  float mx = red[0];
  __syncthreads();
  float e = (t < 196) ? __expf(v - mx) : 0.f;
  red[t] = e;
  __syncthreads();
  for (int s = 128; s > 0; s >>= 1) {
    if (t < s) red[t] += red[t + s];
    __syncthreads();
  }
  float a = e / red[0];
  if (t < 196) {
    alpha_sh[t] = a;
    if (slice == 0) alpha_out[(size_t)b * 196 + t] = a;
  }
  __syncthreads();

  f32x4 acc = {0.f, 0.f, 0.f, 0.f};
  const float* ep = enc + (size_t)b * 196 * 2048 + slice * 1024 + t * 4;
#pragma unroll 4
  for (int p = 0; p < 196; ++p) {
    float ap = alpha_sh[p];
    f32x4 ev = *(const f32x4*)ep;
    acc[0] = fmaf(ap, ev[0], acc[0]);
    acc[1] = fmaf(ap, ev[1], acc[1]);
    acc[2] = fmaf(ap, ev[2], acc[2]);
    acc[3] = fmaf(ap, ev[3], acc[3]);
    ep += 2048;
  }
  *(f32x4*)(ctx_out + (size_t)b * 2048 + slice * 1024 + t * 4) = acc;
}

// ------------------------------------------------------------- launch
extern "C" void kernel_launch(void* const* d_in, const int* in_sizes, int n_in,
                              void* d_out, int out_size, void* d_ws, size_t ws_size,
                              hipStream_t stream) {
  (void)in_sizes; (void)n_in; (void)out_size; (void)ws_size;
  const float* enc   = (const float*)d_in[0];  // [256,196,2048] fp32
  const float* dec   = (const float*)d_in[1];  // [256,512]
  const float* wenc  = (const float*)d_in[2];  // [2048,512]
  const float* benc  = (const float*)d_in[3];  // [512]
  const float* wdec  = (const float*)d_in[4];  // [512,512]
  const float* bdec  = (const float*)d_in[5];  // [512]
  const float* wfull = (const float*)d_in[6];  // [512]
  // d_in[7] (b_full) unused: softmax is shift-invariant.

  unsigned short* wencT = (unsigned short*)d_ws;                    // 2 MB (tiled)
  float* comb = (float*)((char*)d_ws + (2u << 20));                 // 512 KB
  float* att  = (float*)((char*)d_ws + (2u << 20) + (512u << 10));  // 200 KB

  float* ctx_out = (float*)d_out;                    // [256,2048] fp32
  float* alpha_out = ctx_out + (size_t)256 * 2048;   // [256,196]  fp32

  hipLaunchKernelGGL(transpose_wenc, dim3(512), dim3(256), 0, stream, wenc, wencT);
  hipLaunchKernelGGL(comb_kernel, dim3(256), dim3(256), 0, stream, dec, wdec, bdec, benc, comb);
  hipLaunchKernelGGL(gemm_att, dim3(784), dim3(512), 0, stream, enc, wencT, comb, wfull, att);
  hipLaunchKernelGGL(softmax_ctx, dim3(512), dim3(256), 0, stream, att, enc, ctx_out, alpha_out);
}